// Round 6
// baseline (15764.099 us; speedup 1.0000x reference)
//
#include <hip/hip_runtime.h>
#include <hip/hip_bf16.h>
#include <math.h>

// Problem dims
#define T_N   4096
#define IN_N  1024
#define H_N   2048
#define OUT_N 1024

// Recurrence decomposition: KD3 blocks per direction, each owns RPB3 rows of Wh.
#define KD3  64
#define RPB3 32        // H_N / KD3
#define RTH3 1024      // 16 waves, 2 rows per wave

#define SENT 0xFFFFFFFFu   // negative NaN; tanhf output (finite, [-1,1]) never equals it

// Workspace byte offsets
#define XW_F_OFF 0ull
#define XW_B_OFF 33554432ull
#define HF_OFF   67108864ull
#define HB_OFF   100663296ull
// hf+hb are contiguous: sentinel-fill region = [HF_OFF, HF_OFF+64MB)

// Grid-stride sentinel fill of hf+hb (16 MiB of ulong2 = 64 MiB).
__global__ __launch_bounds__(256) void sentinel_fill_kernel(ulonglong2* __restrict__ p) {
  const unsigned long long n = (64ull << 20) / 16ull;   // 4M ulonglong2
  ulonglong2 v; v.x = 0xFFFFFFFFFFFFFFFFull; v.y = 0xFFFFFFFFFFFFFFFFull;
  for (unsigned long long i = blockIdx.x * 256ull + threadIdx.x; i < n;
       i += gridDim.x * 256ull)
    p[i] = v;
}

// ---------------------------------------------------------------------------
// Tiled fp32 NT GEMM: C[m][n] = sum_k A[m][k]*B[n][k] + bias[n]
// 64x64 tile, BK=16, 256 threads, 4x4 per thread.
// ---------------------------------------------------------------------------
__global__ __launch_bounds__(256) void gemm_xw_kernel(
    const float* __restrict__ x,
    const float* __restrict__ Wxf, const float* __restrict__ bhf,
    const float* __restrict__ Wxb, const float* __restrict__ bhb,
    float* __restrict__ xwf, float* __restrict__ xwb)
{
  const int dir = blockIdx.z;
  const float* __restrict__ B    = dir ? Wxb : Wxf;
  const float* __restrict__ bias = dir ? bhb : bhf;
  float* __restrict__ C          = dir ? xwb : xwf;
  const int bm0 = blockIdx.y * 64;   // T dim
  const int bn0 = blockIdx.x * 64;   // H dim

  __shared__ float As[16][65];
  __shared__ float Bs[16][65];
  const int tid  = threadIdx.x;
  const int ty   = tid >> 4, tx = tid & 15;
  const int lrow = tid >> 2, lkq = (tid & 3) << 2;
  float acc[4][4] = {};

  for (int k0 = 0; k0 < IN_N; k0 += 16) {
    float4 a4 = *(const float4*)(x + (size_t)(bm0 + lrow) * IN_N + k0 + lkq);
    float4 b4 = *(const float4*)(B + (size_t)(bn0 + lrow) * IN_N + k0 + lkq);
    As[lkq + 0][lrow] = a4.x; As[lkq + 1][lrow] = a4.y;
    As[lkq + 2][lrow] = a4.z; As[lkq + 3][lrow] = a4.w;
    Bs[lkq + 0][lrow] = b4.x; Bs[lkq + 1][lrow] = b4.y;
    Bs[lkq + 2][lrow] = b4.z; Bs[lkq + 3][lrow] = b4.w;
    __syncthreads();
#pragma unroll
    for (int k = 0; k < 16; ++k) {
      float a[4], b[4];
#pragma unroll
      for (int i = 0; i < 4; ++i) a[i] = As[k][ty * 4 + i];
#pragma unroll
      for (int j = 0; j < 4; ++j) b[j] = Bs[k][tx * 4 + j];
#pragma unroll
      for (int i = 0; i < 4; ++i)
#pragma unroll
        for (int j = 0; j < 4; ++j) acc[i][j] = fmaf(a[i], b[j], acc[i][j]);
    }
    __syncthreads();
  }
#pragma unroll
  for (int i = 0; i < 4; ++i) {
    float4 v;
    v.x = acc[i][0] + bias[bn0 + tx * 4 + 0];
    v.y = acc[i][1] + bias[bn0 + tx * 4 + 1];
    v.z = acc[i][2] + bias[bn0 + tx * 4 + 2];
    v.w = acc[i][3] + bias[bn0 + tx * 4 + 3];
    *(float4*)(C + (size_t)(bm0 + ty * 4 + i) * H_N + bn0 + tx * 4) = v;
  }
}

__global__ __launch_bounds__(256) void gemm_out_kernel(
    const float* __restrict__ hf, const float* __restrict__ hb,
    const float* __restrict__ Wyf, const float* __restrict__ Wyb,
    const float* __restrict__ by, float* __restrict__ y)
{
  const int bm0 = blockIdx.y * 64;   // T dim
  const int bn0 = blockIdx.x * 64;   // OUT dim
  __shared__ float As[16][65];
  __shared__ float Bs[16][65];
  const int tid  = threadIdx.x;
  const int ty   = tid >> 4, tx = tid & 15;
  const int lrow = tid >> 2, lkq = (tid & 3) << 2;
  float acc[4][4] = {};

#pragma unroll 1
  for (int pass = 0; pass < 2; ++pass) {
    const float* __restrict__ A = pass ? hb : hf;
    const float* __restrict__ B = pass ? Wyb : Wyf;
    for (int k0 = 0; k0 < H_N; k0 += 16) {
      float4 a4 = *(const float4*)(A + (size_t)(bm0 + lrow) * H_N + k0 + lkq);
      float4 b4 = *(const float4*)(B + (size_t)(bn0 + lrow) * H_N + k0 + lkq);
      As[lkq + 0][lrow] = a4.x; As[lkq + 1][lrow] = a4.y;
      As[lkq + 2][lrow] = a4.z; As[lkq + 3][lrow] = a4.w;
      Bs[lkq + 0][lrow] = b4.x; Bs[lkq + 1][lrow] = b4.y;
      Bs[lkq + 2][lrow] = b4.z; Bs[lkq + 3][lrow] = b4.w;
      __syncthreads();
#pragma unroll
      for (int k = 0; k < 16; ++k) {
        float a[4], b[4];
#pragma unroll
        for (int i = 0; i < 4; ++i) a[i] = As[k][ty * 4 + i];
#pragma unroll
        for (int j = 0; j < 4; ++j) b[j] = Bs[k][tx * 4 + j];
#pragma unroll
        for (int i = 0; i < 4; ++i)
#pragma unroll
          for (int j = 0; j < 4; ++j) acc[i][j] = fmaf(a[i], b[j], acc[i][j]);
      }
      __syncthreads();
    }
  }
#pragma unroll
  for (int i = 0; i < 4; ++i) {
    float4 v;
    v.x = acc[i][0] + by[bn0 + tx * 4 + 0];
    v.y = acc[i][1] + by[bn0 + tx * 4 + 1];
    v.z = acc[i][2] + by[bn0 + tx * 4 + 2];
    v.w = acc[i][3] + by[bn0 + tx * 4 + 3];
    *(float4*)(y + (size_t)(bm0 + ty * 4 + i) * OUT_N + bn0 + tx * 4) = v;
  }
}

// ---------------------------------------------------------------------------
// Persistent bidirectional recurrence, v6 — SENTINEL DATAFLOW, zero flags.
// h histories are pre-filled with 0xFFFFFFFF (negative NaN). Each thread
// spin-loads its own 8B slice of h[pt] via relaxed agent-scope (LLC-direct)
// atomics until both words != sentinel — the poll IS the staging load (one
// LLC round-trip on the critical path). tanhf output is finite ([-1,1]) so
// real data never equals the sentinel. Producers just fire 2 relaxed stores;
// no flags, no fences, 2 barriers/step instead of 3.
// ---------------------------------------------------------------------------
__global__ __launch_bounds__(RTH3, 4) void recurrent_kernel(
    const float* __restrict__ Whf, const float* __restrict__ Whb,
    const float* __restrict__ xwf, const float* __restrict__ xwb,
    float* __restrict__ hf, float* __restrict__ hb)
{
  const int b    = blockIdx.x;
  const bool fwd = (b < KD3);
  const int bb   = fwd ? b : b - KD3;
  const int rb   = bb * RPB3;
  const float* __restrict__ Wh = fwd ? Whf : Whb;
  const float* __restrict__ xw = fwd ? xwf : xwb;
  float* __restrict__ hist     = fwd ? hf : hb;

  const int w     = threadIdx.x >> 6;   // wave 0..15
  const int lane  = threadIdx.x & 63;
  const int jbase = lane << 2;          // 0..252
  const int r0    = rb + 2 * w;         // this wave's two rows

  __shared__ __align__(16) float hs[H_N];   // 8 KB staged h_prev

  // One-time: weight slice into registers (64 VGPRs/lane), pinned so the
  // loads cannot be sunk into the loop.
  float4 wv[2][8];
#pragma unroll
  for (int q = 0; q < 2; ++q)
#pragma unroll
    for (int k = 0; k < 8; ++k)
      wv[q][k] = *(const float4*)(Wh + (size_t)(r0 + q) * H_N + k * 256 + jbase);
#pragma unroll
  for (int q = 0; q < 2; ++q)
#pragma unroll
    for (int k = 0; k < 8; ++k)
      asm volatile("" : "+v"(wv[q][k].x), "+v"(wv[q][k].y),
                        "+v"(wv[q][k].z), "+v"(wv[q][k].w));

  for (int s = 0; s < T_N; ++s) {
    const int t  = fwd ? s : (T_N - 1 - s);
    const int pt = fwd ? (t - 1) : (t + 1);

    // xw prefetch for our two rows (independent of h; overlaps the spin).
    float xwv0 = 0.f, xwv1 = 0.f;
    if (lane == 0) {
      xwv0 = xw[(size_t)t * H_N + r0 + 0];
      xwv1 = xw[(size_t)t * H_N + r0 + 1];
    }

    if (s > 0) {
      // Per-thread sentinel spin on own 8B slice = poll + staging in one.
      const unsigned long long* src =
          (const unsigned long long*)(hist + (size_t)pt * H_N) + threadIdx.x;
      unsigned long long hv2;
      for (;;) {
        hv2 = __hip_atomic_load(src, __ATOMIC_RELAXED, __HIP_MEMORY_SCOPE_AGENT);
        if ((unsigned)hv2 != SENT && (unsigned)(hv2 >> 32) != SENT) break;
        __builtin_amdgcn_s_sleep(1);
      }
      *((unsigned long long*)hs + threadIdx.x) = hv2;
    } else {
      *((unsigned long long*)hs + threadIdx.x) = 0ull;
    }
    __syncthreads();   // staged h visible to all waves

    // LDS fragments: conflict-free ds_read_b128 (lane-consecutive 16B).
    float acc0 = 0.f, acc1 = 0.f;
#pragma unroll
    for (int k = 0; k < 8; ++k) {
      float4 h4 = *(const float4*)(hs + k * 256 + jbase);
      acc0 = fmaf(wv[0][k].x, h4.x, acc0);
      acc0 = fmaf(wv[0][k].y, h4.y, acc0);
      acc0 = fmaf(wv[0][k].z, h4.z, acc0);
      acc0 = fmaf(wv[0][k].w, h4.w, acc0);
      acc1 = fmaf(wv[1][k].x, h4.x, acc1);
      acc1 = fmaf(wv[1][k].y, h4.y, acc1);
      acc1 = fmaf(wv[1][k].z, h4.z, acc1);
      acc1 = fmaf(wv[1][k].w, h4.w, acc1);
    }
#pragma unroll
    for (int off = 32; off > 0; off >>= 1) {
      acc0 += __shfl_xor(acc0, off, 64);
      acc1 += __shfl_xor(acc1, off, 64);
    }

    if (lane == 0) {
      union { float f; unsigned u; } h0, h1;
      h0.f = tanhf(acc0 + xwv0);
      h1.f = tanhf(acc1 + xwv1);
      unsigned* hu = (unsigned*)(hist + (size_t)t * H_N + r0);
      __hip_atomic_store(hu + 0, h0.u, __ATOMIC_RELAXED, __HIP_MEMORY_SCOPE_AGENT);
      __hip_atomic_store(hu + 1, h1.u, __ATOMIC_RELAXED, __HIP_MEMORY_SCOPE_AGENT);
    }

    __syncthreads();   // WAR: hs consumed by all waves before next overwrite
  }
}

extern "C" void kernel_launch(void* const* d_in, const int* in_sizes, int n_in,
                              void* d_out, int out_size, void* d_ws, size_t ws_size,
                              hipStream_t stream) {
  const float* x   = (const float*)d_in[0];
  const float* Wxf = (const float*)d_in[1];
  const float* Whf = (const float*)d_in[2];
  const float* bhf = (const float*)d_in[3];
  const float* Wxb = (const float*)d_in[4];
  const float* Whb = (const float*)d_in[5];
  const float* bhb = (const float*)d_in[6];
  const float* Wyf = (const float*)d_in[7];
  const float* Wyb = (const float*)d_in[8];
  const float* by  = (const float*)d_in[9];
  float* y = (float*)d_out;

  char* ws = (char*)d_ws;
  float* xwf = (float*)(ws + XW_F_OFF);
  float* xwb = (float*)(ws + XW_B_OFF);
  float* hf  = (float*)(ws + HF_OFF);
  float* hb  = (float*)(ws + HB_OFF);

  // Re-fill h histories with sentinel every call (harness doesn't re-poison).
  hipLaunchKernelGGL(sentinel_fill_kernel, dim3(1024), dim3(256), 0, stream,
                     (ulonglong2*)(ws + HF_OFF));
  hipLaunchKernelGGL(gemm_xw_kernel, dim3(H_N / 64, T_N / 64, 2), dim3(256), 0, stream,
                     x, Wxf, bhf, Wxb, bhb, xwf, xwb);
  hipLaunchKernelGGL(recurrent_kernel, dim3(2 * KD3), dim3(RTH3), 0, stream,
                     Whf, Whb, xwf, xwb, hf, hb);
  hipLaunchKernelGGL(gemm_out_kernel, dim3(OUT_N / 64, T_N / 64), dim3(256), 0, stream,
                     hf, hb, Wyf, Wyb, by, y);
}

// Round 7
// 13139.352 us; speedup vs baseline: 1.1998x; 1.1998x over previous
//
#include <hip/hip_runtime.h>
#include <hip/hip_bf16.h>
#include <math.h>

// Problem dims
#define T_N   4096
#define IN_N  1024
#define H_N   2048
#define OUT_N 1024

// Recurrence decomposition: KD blocks per direction, each owns RPB rows of Wh.
#define KD3  64
#define RPB3 32        // H_N / KD3
#define RTH3 512       // 8 waves, 4 rows per wave

// Workspace byte offsets (total 128 MiB + 512 B)
#define XW_F_OFF 0ull
#define XW_B_OFF 33554432ull
#define HF_OFF   67108864ull
#define HB_OFF   100663296ull
#define PROG_OFF 134217728ull    // progf: 64 u32 @ +0, progb: 64 u32 @ +256B

__global__ __launch_bounds__(128) void init_prog_kernel(unsigned* __restrict__ p) {
  p[threadIdx.x] = 0u;   // resets both directions' counters (128 words)
}

// ---------------------------------------------------------------------------
// Tiled fp32 NT GEMM: C[m][n] = sum_k A[m][k]*B[n][k] + bias[n]
// 64x64 tile, BK=16, 256 threads, 4x4 per thread.
// ---------------------------------------------------------------------------
__global__ __launch_bounds__(256) void gemm_xw_kernel(
    const float* __restrict__ x,
    const float* __restrict__ Wxf, const float* __restrict__ bhf,
    const float* __restrict__ Wxb, const float* __restrict__ bhb,
    float* __restrict__ xwf, float* __restrict__ xwb)
{
  const int dir = blockIdx.z;
  const float* __restrict__ B    = dir ? Wxb : Wxf;
  const float* __restrict__ bias = dir ? bhb : bhf;
  float* __restrict__ C          = dir ? xwb : xwf;
  const int bm0 = blockIdx.y * 64;   // T dim
  const int bn0 = blockIdx.x * 64;   // H dim

  __shared__ float As[16][65];
  __shared__ float Bs[16][65];
  const int tid  = threadIdx.x;
  const int ty   = tid >> 4, tx = tid & 15;
  const int lrow = tid >> 2, lkq = (tid & 3) << 2;
  float acc[4][4] = {};

  for (int k0 = 0; k0 < IN_N; k0 += 16) {
    float4 a4 = *(const float4*)(x + (size_t)(bm0 + lrow) * IN_N + k0 + lkq);
    float4 b4 = *(const float4*)(B + (size_t)(bn0 + lrow) * IN_N + k0 + lkq);
    As[lkq + 0][lrow] = a4.x; As[lkq + 1][lrow] = a4.y;
    As[lkq + 2][lrow] = a4.z; As[lkq + 3][lrow] = a4.w;
    Bs[lkq + 0][lrow] = b4.x; Bs[lkq + 1][lrow] = b4.y;
    Bs[lkq + 2][lrow] = b4.z; Bs[lkq + 3][lrow] = b4.w;
    __syncthreads();
#pragma unroll
    for (int k = 0; k < 16; ++k) {
      float a[4], b[4];
#pragma unroll
      for (int i = 0; i < 4; ++i) a[i] = As[k][ty * 4 + i];
#pragma unroll
      for (int j = 0; j < 4; ++j) b[j] = Bs[k][tx * 4 + j];
#pragma unroll
      for (int i = 0; i < 4; ++i)
#pragma unroll
        for (int j = 0; j < 4; ++j) acc[i][j] = fmaf(a[i], b[j], acc[i][j]);
    }
    __syncthreads();
  }
#pragma unroll
  for (int i = 0; i < 4; ++i) {
    float4 v;
    v.x = acc[i][0] + bias[bn0 + tx * 4 + 0];
    v.y = acc[i][1] + bias[bn0 + tx * 4 + 1];
    v.z = acc[i][2] + bias[bn0 + tx * 4 + 2];
    v.w = acc[i][3] + bias[bn0 + tx * 4 + 3];
    *(float4*)(C + (size_t)(bm0 + ty * 4 + i) * H_N + bn0 + tx * 4) = v;
  }
}

__global__ __launch_bounds__(256) void gemm_out_kernel(
    const float* __restrict__ hf, const float* __restrict__ hb,
    const float* __restrict__ Wyf, const float* __restrict__ Wyb,
    const float* __restrict__ by, float* __restrict__ y)
{
  const int bm0 = blockIdx.y * 64;   // T dim
  const int bn0 = blockIdx.x * 64;   // OUT dim
  __shared__ float As[16][65];
  __shared__ float Bs[16][65];
  const int tid  = threadIdx.x;
  const int ty   = tid >> 4, tx = tid & 15;
  const int lrow = tid >> 2, lkq = (tid & 3) << 2;
  float acc[4][4] = {};

#pragma unroll 1
  for (int pass = 0; pass < 2; ++pass) {
    const float* __restrict__ A = pass ? hb : hf;
    const float* __restrict__ B = pass ? Wyb : Wyf;
    for (int k0 = 0; k0 < H_N; k0 += 16) {
      float4 a4 = *(const float4*)(A + (size_t)(bm0 + lrow) * H_N + k0 + lkq);
      float4 b4 = *(const float4*)(B + (size_t)(bn0 + lrow) * H_N + k0 + lkq);
      As[lkq + 0][lrow] = a4.x; As[lkq + 1][lrow] = a4.y;
      As[lkq + 2][lrow] = a4.z; As[lkq + 3][lrow] = a4.w;
      Bs[lkq + 0][lrow] = b4.x; Bs[lkq + 1][lrow] = b4.y;
      Bs[lkq + 2][lrow] = b4.z; Bs[lkq + 3][lrow] = b4.w;
      __syncthreads();
#pragma unroll
      for (int k = 0; k < 16; ++k) {
        float a[4], b[4];
#pragma unroll
        for (int i = 0; i < 4; ++i) a[i] = As[k][ty * 4 + i];
#pragma unroll
        for (int j = 0; j < 4; ++j) b[j] = Bs[k][tx * 4 + j];
#pragma unroll
        for (int i = 0; i < 4; ++i)
#pragma unroll
          for (int j = 0; j < 4; ++j) acc[i][j] = fmaf(a[i], b[j], acc[i][j]);
      }
      __syncthreads();
    }
  }
#pragma unroll
  for (int i = 0; i < 4; ++i) {
    float4 v;
    v.x = acc[i][0] + by[bn0 + tx * 4 + 0];
    v.y = acc[i][1] + by[bn0 + tx * 4 + 1];
    v.z = acc[i][2] + by[bn0 + tx * 4 + 2];
    v.w = acc[i][3] + by[bn0 + tx * 4 + 3];
    *(float4*)(y + (size_t)(bm0 + ty * 4 + i) * OUT_N + bn0 + tx * 4) = v;
  }
}

// ---------------------------------------------------------------------------
// Persistent bidirectional recurrence, v7 — v5 fenceless-flag structure with
// trimmed overhead. 128 blocks x 512 threads (8 waves, 4 rows/wave; weight
// slice wv[4][8] = 128 VGPRs/lane, pinned). Per step:
//   wave0 hot-spins (no s_sleep) on 64 per-block flags via relaxed
//   agent-scope (LLC-direct) loads -> barrier -> all threads stage h_prev
//   (2x 8B atomic loads each) into LDS -> barrier -> 128 FMA/lane +
//   butterfly reduce x4 -> lane0 packs 4 rows into 2x 8B atomic stores ->
//   end barrier (drains vmcnt: stores ACKed at LLC) -> tid0 relaxed flag
//   store. Zero HW fences; LLC is the coherence point for all exchange.
// v6 lesson baked in: polls touch ONLY the 4 flag cache lines, never data.
// ---------------------------------------------------------------------------
__global__ __launch_bounds__(RTH3, 2) void recurrent_kernel(
    const float* __restrict__ Whf, const float* __restrict__ Whb,
    const float* __restrict__ xwf, const float* __restrict__ xwb,
    float* __restrict__ hf, float* __restrict__ hb,
    unsigned* __restrict__ progf, unsigned* __restrict__ progb)
{
  const int b    = blockIdx.x;
  const bool fwd = (b < KD3);
  const int bb   = fwd ? b : b - KD3;
  const int rb   = bb * RPB3;
  const float* __restrict__ Wh = fwd ? Whf : Whb;
  const float* __restrict__ xw = fwd ? xwf : xwb;
  float* __restrict__ hist     = fwd ? hf : hb;
  unsigned* __restrict__ prog  = fwd ? progf : progb;

  const int w     = threadIdx.x >> 6;   // wave 0..7
  const int lane  = threadIdx.x & 63;
  const int jbase = lane << 2;          // 0..252
  const int r0    = rb + 4 * w;         // this wave's four rows

  __shared__ __align__(16) float hs[H_N];   // 8 KB staged h_prev

  // One-time: weight slice into registers (128 VGPRs/lane), pinned so the
  // loads cannot be sunk into the loop.
  float4 wv[4][8];
#pragma unroll
  for (int q = 0; q < 4; ++q)
#pragma unroll
    for (int k = 0; k < 8; ++k)
      wv[q][k] = *(const float4*)(Wh + (size_t)(r0 + q) * H_N + k * 256 + jbase);
#pragma unroll
  for (int q = 0; q < 4; ++q)
#pragma unroll
    for (int k = 0; k < 8; ++k)
      asm volatile("" : "+v"(wv[q][k].x), "+v"(wv[q][k].y),
                        "+v"(wv[q][k].z), "+v"(wv[q][k].w));

  for (int s = 0; s < T_N; ++s) {
    const int t  = fwd ? s : (T_N - 1 - s);
    const int pt = fwd ? (t - 1) : (t + 1);

    // xw prefetch for our four rows (independent of h; overlaps the poll).
    float4 xwv = make_float4(0.f, 0.f, 0.f, 0.f);
    if (lane == 0)
      xwv = *(const float4*)(xw + (size_t)t * H_N + r0);

    if (s > 0) {
      if (w == 0) {
        for (;;) {   // hot spin — only 128 wave0s on 4 flag cache lines
          unsigned p = __hip_atomic_load(prog + lane, __ATOMIC_RELAXED,
                                         __HIP_MEMORY_SCOPE_AGENT);
          if (__all(p >= (unsigned)s)) break;
        }
        asm volatile("" ::: "memory");   // compiler barrier only
      }
      __syncthreads();
      // Cooperative stage from LLC: 512 threads x two 8B relaxed atomics.
      const unsigned long long* src =
          (const unsigned long long*)(hist + (size_t)pt * H_N);
      unsigned long long h0 = __hip_atomic_load(src + 2 * threadIdx.x + 0,
          __ATOMIC_RELAXED, __HIP_MEMORY_SCOPE_AGENT);
      unsigned long long h1 = __hip_atomic_load(src + 2 * threadIdx.x + 1,
          __ATOMIC_RELAXED, __HIP_MEMORY_SCOPE_AGENT);
      ((unsigned long long*)hs)[2 * threadIdx.x + 0] = h0;
      ((unsigned long long*)hs)[2 * threadIdx.x + 1] = h1;
    } else {
      ((unsigned long long*)hs)[2 * threadIdx.x + 0] = 0ull;
      ((unsigned long long*)hs)[2 * threadIdx.x + 1] = 0ull;
    }
    __syncthreads();   // staged h visible to all waves

    // LDS fragments: conflict-free ds_read_b128 (lane-consecutive 16B).
    float acc0 = 0.f, acc1 = 0.f, acc2 = 0.f, acc3 = 0.f;
#pragma unroll
    for (int k = 0; k < 8; ++k) {
      float4 h4 = *(const float4*)(hs + k * 256 + jbase);
      acc0 = fmaf(wv[0][k].x, h4.x, acc0); acc0 = fmaf(wv[0][k].y, h4.y, acc0);
      acc0 = fmaf(wv[0][k].z, h4.z, acc0); acc0 = fmaf(wv[0][k].w, h4.w, acc0);
      acc1 = fmaf(wv[1][k].x, h4.x, acc1); acc1 = fmaf(wv[1][k].y, h4.y, acc1);
      acc1 = fmaf(wv[1][k].z, h4.z, acc1); acc1 = fmaf(wv[1][k].w, h4.w, acc1);
      acc2 = fmaf(wv[2][k].x, h4.x, acc2); acc2 = fmaf(wv[2][k].y, h4.y, acc2);
      acc2 = fmaf(wv[2][k].z, h4.z, acc2); acc2 = fmaf(wv[2][k].w, h4.w, acc2);
      acc3 = fmaf(wv[3][k].x, h4.x, acc3); acc3 = fmaf(wv[3][k].y, h4.y, acc3);
      acc3 = fmaf(wv[3][k].z, h4.z, acc3); acc3 = fmaf(wv[3][k].w, h4.w, acc3);
    }
#pragma unroll
    for (int off = 32; off > 0; off >>= 1) {
      acc0 += __shfl_xor(acc0, off, 64);
      acc1 += __shfl_xor(acc1, off, 64);
      acc2 += __shfl_xor(acc2, off, 64);
      acc3 += __shfl_xor(acc3, off, 64);
    }

    if (lane == 0) {
      union { float f; unsigned u; } r[4];
      r[0].f = tanhf(acc0 + xwv.x);
      r[1].f = tanhf(acc1 + xwv.y);
      r[2].f = tanhf(acc2 + xwv.z);
      r[3].f = tanhf(acc3 + xwv.w);
      unsigned long long p0 = ((unsigned long long)r[1].u << 32) | r[0].u;
      unsigned long long p1 = ((unsigned long long)r[3].u << 32) | r[2].u;
      unsigned long long* dst =
          (unsigned long long*)(hist + (size_t)t * H_N + r0);
      __hip_atomic_store(dst + 0, p0, __ATOMIC_RELAXED, __HIP_MEMORY_SCOPE_AGENT);
      __hip_atomic_store(dst + 1, p1, __ATOMIC_RELAXED, __HIP_MEMORY_SCOPE_AGENT);
    }

    // Per-wave s_waitcnt vmcnt(0) before s_barrier: all 32 row-stores are
    // ACKed at the LLC once the barrier releases. Also WAR-protects hs.
    __syncthreads();
    if (threadIdx.x == 0)
      __hip_atomic_store(prog + bb, (unsigned)(s + 1), __ATOMIC_RELAXED,
                         __HIP_MEMORY_SCOPE_AGENT);
  }
}

extern "C" void kernel_launch(void* const* d_in, const int* in_sizes, int n_in,
                              void* d_out, int out_size, void* d_ws, size_t ws_size,
                              hipStream_t stream) {
  const float* x   = (const float*)d_in[0];
  const float* Wxf = (const float*)d_in[1];
  const float* Whf = (const float*)d_in[2];
  const float* bhf = (const float*)d_in[3];
  const float* Wxb = (const float*)d_in[4];
  const float* Whb = (const float*)d_in[5];
  const float* bhb = (const float*)d_in[6];
  const float* Wyf = (const float*)d_in[7];
  const float* Wyb = (const float*)d_in[8];
  const float* by  = (const float*)d_in[9];
  float* y = (float*)d_out;

  char* ws = (char*)d_ws;
  float* xwf      = (float*)(ws + XW_F_OFF);
  float* xwb      = (float*)(ws + XW_B_OFF);
  float* hf       = (float*)(ws + HF_OFF);
  float* hb       = (float*)(ws + HB_OFF);
  unsigned* progf = (unsigned*)(ws + PROG_OFF);
  unsigned* progb = progf + 64;   // +256 B, separate cache line

  hipLaunchKernelGGL(init_prog_kernel, dim3(1), dim3(128), 0, stream, progf);
  hipLaunchKernelGGL(gemm_xw_kernel, dim3(H_N / 64, T_N / 64, 2), dim3(256), 0, stream,
                     x, Wxf, bhf, Wxb, bhb, xwf, xwb);
  hipLaunchKernelGGL(recurrent_kernel, dim3(2 * KD3), dim3(RTH3), 0, stream,
                     Whf, Whb, xwf, xwb, hf, hb, progf, progb);
  hipLaunchKernelGGL(gemm_out_kernel, dim3(OUT_N / 64, T_N / 64), dim3(256), 0, stream,
                     hf, hb, Wyf, Wyb, by, y);
}